// Round 1
// baseline (1383.875 us; speedup 1.0000x reference)
//
#include <hip/hip_runtime.h>
#include <hip/hip_bf16.h>

// GCN 2-layer forward on MI355X. All f32.
// Inputs: x[N,128], src[E], dst[E], W1[128,64], b1[64], W2[64,8], b2[8]
// Output: softmax probs [N,8] f32.

#define IN_DIM 128
#define HID 64
#define NC 8

__global__ void deg_k(const int* __restrict__ src, const int* __restrict__ dst,
                      float* __restrict__ deg_out, float* __restrict__ deg_in, int e) {
    int i = blockIdx.x * blockDim.x + threadIdx.x;
    if (i < e) {
        atomicAdd(&deg_out[src[i]], 1.0f);
        atomicAdd(&deg_in[dst[i]], 1.0f);
    }
}

__global__ void norm_k(float* __restrict__ deg_out, float* __restrict__ deg_in, int n) {
    int i = blockIdx.x * blockDim.x + threadIdx.x;
    if (i < n) {
        deg_out[i] = rsqrtf(fmaxf(deg_out[i], 1.0f));
        deg_in[i]  = rsqrtf(fmaxf(deg_in[i], 1.0f));
    }
}

// h0[i][j] = out_norm[i] * sum_k x[i][k] * W1[k][j]
// block: 256 threads = 4 rows x 64 cols. W1 (32KB) + 4 x-rows staged in LDS.
__global__ void gemm1_k(const float* __restrict__ x, const float* __restrict__ W1,
                        const float* __restrict__ out_norm, float* __restrict__ h0, int n) {
    __shared__ float Ws[IN_DIM * HID];   // 32 KB
    __shared__ float xs[4 * IN_DIM];     // 2 KB
    int t = threadIdx.x;
    for (int i = t; i < IN_DIM * HID; i += 256) Ws[i] = W1[i];
    int row0 = blockIdx.x * 4;
    for (int i = t; i < 4 * IN_DIM; i += 256) {
        int r = row0 + (i >> 7);
        xs[i] = (r < n) ? x[r * IN_DIM + (i & 127)] : 0.0f;
    }
    __syncthreads();
    int rl = t >> 6;        // 0..3
    int col = t & 63;
    int row = row0 + rl;
    if (row < n) {
        float acc = 0.0f;
#pragma unroll
        for (int k = 0; k < IN_DIM; ++k) acc += xs[rl * IN_DIM + k] * Ws[k * HID + col];
        h0[row * HID + col] = acc * out_norm[row];
    }
}

// one wave per edge, lane = hidden column. Coalesced 256B gather + 256B atomic scatter.
__global__ void scat1_k(const int* __restrict__ src, const int* __restrict__ dst,
                        const float* __restrict__ h0, float* __restrict__ agg1, int e) {
    int gid = blockIdx.x * blockDim.x + threadIdx.x;
    int eid = gid >> 6;
    int lane = threadIdx.x & 63;
    if (eid < e) {
        int s = src[eid];
        int d = dst[eid];
        atomicAdd(&agg1[d * HID + lane], h0[s * HID + lane]);
    }
}

// h2p[i][c] = out_norm[i] * sum_j relu(agg1[i][j]*in_norm[i] + b1[j]) * W2[j][c]
// block: 256 threads = 32 nodes x 8 classes. agg1 rows staged in LDS (padded).
__global__ void fuse2_k(const float* __restrict__ agg1, const float* __restrict__ in_norm,
                        const float* __restrict__ out_norm, const float* __restrict__ b1,
                        const float* __restrict__ W2, float* __restrict__ h2p, int n) {
    __shared__ float as[32 * 65];   // pad to 65 to avoid bank conflicts
    __shared__ float Ws[HID * NC];  // 2 KB
    __shared__ float b1s[HID];
    int t = threadIdx.x;
    for (int i = t; i < HID * NC; i += 256) Ws[i] = W2[i];
    if (t < HID) b1s[t] = b1[t];
    int node0 = blockIdx.x * 32;
    for (int i = t; i < 32 * HID; i += 256) {
        int r = node0 + (i >> 6);
        as[(i >> 6) * 65 + (i & 63)] = (r < n) ? agg1[r * HID + (i & 63)] : 0.0f;
    }
    __syncthreads();
    int nl = t >> 3;    // 0..31
    int c = t & 7;
    int node = node0 + nl;
    if (node < n) {
        float inn = in_norm[node];
        float onn = out_norm[node];
        float acc = 0.0f;
#pragma unroll
        for (int j = 0; j < HID; ++j) {
            float hv = fmaxf(as[nl * 65 + j] * inn + b1s[j], 0.0f);
            acc += hv * Ws[j * NC + c];
        }
        h2p[node * NC + c] = acc * onn;
    }
}

// thread per (edge, class)
__global__ void scat2_k(const int* __restrict__ src, const int* __restrict__ dst,
                        const float* __restrict__ h2p, float* __restrict__ agg2, int e) {
    int gid = blockIdx.x * blockDim.x + threadIdx.x;
    int eid = gid >> 3;
    int c = gid & 7;
    if (eid < e) {
        atomicAdd(&agg2[dst[eid] * NC + c], h2p[src[eid] * NC + c]);
    }
}

// out[i][c] = softmax_c(agg2[i][c]*in_norm[i] + b2[c])
__global__ void smax_k(const float* __restrict__ agg2, const float* __restrict__ in_norm,
                       const float* __restrict__ b2, float* __restrict__ out, int n) {
    int i = blockIdx.x * blockDim.x + threadIdx.x;
    if (i < n) {
        float inn = in_norm[i];
        float v[NC];
        float m = -1e30f;
#pragma unroll
        for (int c = 0; c < NC; ++c) {
            v[c] = agg2[i * NC + c] * inn + b2[c];
            m = fmaxf(m, v[c]);
        }
        float s = 0.0f;
#pragma unroll
        for (int c = 0; c < NC; ++c) {
            v[c] = expf(v[c] - m);
            s += v[c];
        }
        float r = 1.0f / s;
#pragma unroll
        for (int c = 0; c < NC; ++c) out[i * NC + c] = v[c] * r;
    }
}

extern "C" void kernel_launch(void* const* d_in, const int* in_sizes, int n_in,
                              void* d_out, int out_size, void* d_ws, size_t ws_size,
                              hipStream_t stream) {
    const float* x   = (const float*)d_in[0];
    const int*   src = (const int*)d_in[1];
    const int*   dst = (const int*)d_in[2];
    const float* W1  = (const float*)d_in[3];
    const float* b1  = (const float*)d_in[4];
    const float* W2  = (const float*)d_in[5];
    const float* b2  = (const float*)d_in[6];
    float* out = (float*)d_out;

    const int N = in_sizes[0] / IN_DIM;   // 100000
    const int E = in_sizes[1];            // 3200000

    float* ws = (float*)d_ws;
    float* out_norm = ws;                       // N
    float* in_norm  = ws + (size_t)N;           // N
    float* h0       = ws + (size_t)2 * N;       // 64N
    float* agg1     = ws + (size_t)(2 + 64) * N;   // 64N
    float* h2p      = ws + (size_t)(2 + 128) * N;  // 8N
    float* agg2     = ws + (size_t)(2 + 136) * N;  // 8N  -> total 146N floats

    // zero the accumulators (ws is poisoned 0xAA before every call)
    hipMemsetAsync(out_norm, 0, (size_t)2 * N * sizeof(float), stream);
    hipMemsetAsync(agg1, 0, (size_t)64 * N * sizeof(float), stream);
    hipMemsetAsync(agg2, 0, (size_t)NC * N * sizeof(float), stream);

    deg_k<<<(E + 255) / 256, 256, 0, stream>>>(src, dst, out_norm, in_norm, E);
    norm_k<<<(N + 255) / 256, 256, 0, stream>>>(out_norm, in_norm, N);
    gemm1_k<<<(N + 3) / 4, 256, 0, stream>>>(x, W1, out_norm, h0, N);
    {
        long long threads = (long long)E * 64;
        scat1_k<<<(int)((threads + 255) / 256), 256, 0, stream>>>(src, dst, h0, agg1, E);
    }
    fuse2_k<<<(N + 31) / 32, 256, 0, stream>>>(agg1, in_norm, out_norm, b1, W2, h2p, N);
    {
        long long threads = (long long)E * NC;
        scat2_k<<<(int)((threads + 255) / 256), 256, 0, stream>>>(src, dst, h2p, agg2, E);
    }
    smax_k<<<(N + 255) / 256, 256, 0, stream>>>(agg2, in_norm, b2, out, N);
}

// Round 2
// 897.573 us; speedup vs baseline: 1.5418x; 1.5418x over previous
//
#include <hip/hip_runtime.h>
#include <hip/hip_bf16.h>

// GCN 2-layer forward, CSR pull-based aggregation (no float atomics on features).
// x[N,128] f32, src[E], dst[E] i32, W1[128,64], b1[64], W2[64,8], b2[8]
// out: softmax probs [N,8] f32.

#define IN_DIM 128
#define HID 64
#define NC 8
#define XS_LD 132   // padded leading dim for x tile in LDS (bank-conflict fix)

// degree histogram via float atomics (counts <= 2^24 exact in f32)
__global__ void hist_k(const int* __restrict__ src, const int* __restrict__ dst,
                       float* __restrict__ degf_out, float* __restrict__ degf_in, int e) {
    int i = blockIdx.x * blockDim.x + threadIdx.x;
    if (i < e) {
        atomicAdd(&degf_out[src[i]], 1.0f);
        atomicAdd(&degf_in[dst[i]], 1.0f);
    }
}

// block sums of in-degree (read as float, exact integer)
__global__ void scanA(const float* __restrict__ degf, int* __restrict__ bsum, int n) {
    int t = threadIdx.x;
    int i = blockIdx.x * 256 + t;
    int v = (i < n) ? (int)degf[i] : 0;
#pragma unroll
    for (int d = 1; d < 64; d <<= 1) v += __shfl_xor(v, d, 64);
    __shared__ int w4[4];
    if ((t & 63) == 0) w4[t >> 6] = v;
    __syncthreads();
    if (t == 0) bsum[blockIdx.x] = w4[0] + w4[1] + w4[2] + w4[3];
}

// exclusive scan of block sums (nb <= 512), also writes rowptr[n] = E
__global__ void scanB(int* __restrict__ bsum, int nb, int* __restrict__ rowptr, int n) {
    __shared__ int s[512];
    int t = threadIdx.x;
    s[t] = (t < nb) ? bsum[t] : 0;
    __syncthreads();
    for (int d = 1; d < 512; d <<= 1) {
        int v = (t >= d) ? s[t - d] : 0;
        __syncthreads();
        s[t] += v;
        __syncthreads();
    }
    if (t < nb) bsum[t] = t ? s[t - 1] : 0;
    if (t == 0) rowptr[n] = s[nb - 1];
}

// per-block exclusive scan + block offset -> rowptr & cursor
__global__ void scanC(const float* __restrict__ degf, const int* __restrict__ bsum,
                      int* __restrict__ rowptr, int* __restrict__ cursor, int n) {
    __shared__ int s[256];
    int t = threadIdx.x;
    int i = blockIdx.x * 256 + t;
    int v = (i < n) ? (int)degf[i] : 0;
    s[t] = v;
    __syncthreads();
    for (int d = 1; d < 256; d <<= 1) {
        int u = (t >= d) ? s[t - d] : 0;
        __syncthreads();
        s[t] += u;
        __syncthreads();
    }
    if (i < n) {
        int ex = bsum[blockIdx.x] + s[t] - v;
        rowptr[i] = ex;
        cursor[i] = ex;
    }
}

// convert float degrees -> rsqrt norms, in place
__global__ void norm_k(float* __restrict__ degf_out, float* __restrict__ degf_in, int n) {
    int i = blockIdx.x * blockDim.x + threadIdx.x;
    if (i < n) {
        degf_out[i] = rsqrtf(fmaxf(degf_out[i], 1.0f));
        degf_in[i]  = rsqrtf(fmaxf(degf_in[i], 1.0f));
    }
}

// scatter edge sources into CSR slots (3.2M int atomics)
__global__ void fill_k(const int* __restrict__ src, const int* __restrict__ dst,
                       int* __restrict__ cursor, int* __restrict__ csr, int e) {
    int i = blockIdx.x * blockDim.x + threadIdx.x;
    if (i < e) {
        int d = dst[i];
        int slot = atomicAdd(&cursor[d], 1);
        csr[slot] = src[i];
    }
}

// h0[i][j] = out_norm[i] * (x[i] @ W1)[j]
// 64x64 tile per 256-thread block, 4x4 register tile per thread, float4 LDS reads.
__global__ __launch_bounds__(256) void gemm1_k(const float* __restrict__ x, const float* __restrict__ W1,
                        const float* __restrict__ out_norm, float* __restrict__ h0, int n) {
    __shared__ float xs[64 * XS_LD];   // ~33 KB
    __shared__ float Ws[IN_DIM * HID]; // 32 KB
    int t = threadIdx.x;
    int row0 = blockIdx.x * 64;
#pragma unroll
    for (int j = 0; j < 8; ++j) {
        int f4 = t + j * 256;  // 2048 float4 = 128x64
        *(float4*)&Ws[f4 * 4] = ((const float4*)W1)[f4];
    }
#pragma unroll
    for (int j = 0; j < 8; ++j) {
        int f4 = t + j * 256;  // 2048 float4 = 64 rows x 32
        int r = f4 >> 5;
        int k = (f4 & 31) * 4;
        float4 v = (row0 + r < n) ? ((const float4*)x)[(size_t)(row0 + r) * 32 + (f4 & 31)]
                                  : make_float4(0.f, 0.f, 0.f, 0.f);
        *(float4*)&xs[r * XS_LD + k] = v;
    }
    __syncthreads();
    int rq = (t >> 4) * 4;   // row quad
    int cq = (t & 15) * 4;   // col quad
    float acc[4][4] = {};
    for (int k = 0; k < IN_DIM; k += 4) {
        float4 xr[4], wc[4];
#pragma unroll
        for (int i = 0; i < 4; ++i) xr[i] = *(const float4*)&xs[(rq + i) * XS_LD + k];
#pragma unroll
        for (int kk = 0; kk < 4; ++kk) wc[kk] = *(const float4*)&Ws[(k + kk) * HID + cq];
#pragma unroll
        for (int i = 0; i < 4; ++i) {
            float xv0 = xr[i].x, xv1 = xr[i].y, xv2 = xr[i].z, xv3 = xr[i].w;
            acc[i][0] += xv0 * wc[0].x + xv1 * wc[1].x + xv2 * wc[2].x + xv3 * wc[3].x;
            acc[i][1] += xv0 * wc[0].y + xv1 * wc[1].y + xv2 * wc[2].y + xv3 * wc[3].y;
            acc[i][2] += xv0 * wc[0].z + xv1 * wc[1].z + xv2 * wc[2].z + xv3 * wc[3].z;
            acc[i][3] += xv0 * wc[0].w + xv1 * wc[1].w + xv2 * wc[2].w + xv3 * wc[3].w;
        }
    }
#pragma unroll
    for (int i = 0; i < 4; ++i) {
        int row = row0 + rq + i;
        if (row < n) {
            float onn = out_norm[row];
            float4 o = make_float4(acc[i][0] * onn, acc[i][1] * onn, acc[i][2] * onn, acc[i][3] * onn);
            *(float4*)&h0[(size_t)row * HID + cq] = o;
        }
    }
}

// wave per dst node: pull-aggregate h0 rows, then relu/norm/bias + W2 projection
// via cross-lane reductions. Writes h2p[node][0..7] = out_norm * (relu(...) @ W2).
__global__ void agg1proj_k(const int* __restrict__ rowptr, const int* __restrict__ csr,
                           const float* __restrict__ h0, const float* __restrict__ in_norm,
                           const float* __restrict__ out_norm, const float* __restrict__ b1,
                           const float* __restrict__ W2, float* __restrict__ h2p, int n) {
    int wid = (blockIdx.x * blockDim.x + threadIdx.x) >> 6;
    int lane = threadIdx.x & 63;
    if (wid >= n) return;
    int beg = rowptr[wid], end = rowptr[wid + 1];
    float acc = 0.f;
    int j = beg;
    for (; j + 4 <= end; j += 4) {
        int s0 = csr[j], s1 = csr[j + 1], s2 = csr[j + 2], s3 = csr[j + 3];
        float a0 = h0[(size_t)s0 * HID + lane];
        float a1 = h0[(size_t)s1 * HID + lane];
        float a2 = h0[(size_t)s2 * HID + lane];
        float a3 = h0[(size_t)s3 * HID + lane];
        acc += a0; acc += a1; acc += a2; acc += a3;
    }
    for (; j < end; ++j) acc += h0[(size_t)csr[j] * HID + lane];
    float v = fmaxf(acc * in_norm[wid] + b1[lane], 0.f);
    float onn = out_norm[wid];
    float res = 0.f;
#pragma unroll
    for (int c = 0; c < NC; ++c) {
        float p = v * W2[lane * NC + c];
        p += __shfl_xor(p, 1, 64);
        p += __shfl_xor(p, 2, 64);
        p += __shfl_xor(p, 4, 64);
        p += __shfl_xor(p, 8, 64);
        p += __shfl_xor(p, 16, 64);
        p += __shfl_xor(p, 32, 64);
        if (lane == c) res = p;
    }
    if (lane < NC) h2p[(size_t)wid * NC + lane] = onn * res;
}

// wave per dst node: pull-aggregate h2p rows (8 edges x 8 classes per pass),
// then bias + softmax across the 8-lane class groups. Writes final output.
__global__ void agg2smax_k(const int* __restrict__ rowptr, const int* __restrict__ csr,
                           const float* __restrict__ h2p, const float* __restrict__ in_norm,
                           const float* __restrict__ b2, float* __restrict__ out, int n) {
    int wid = (blockIdx.x * blockDim.x + threadIdx.x) >> 6;
    int lane = threadIdx.x & 63;
    if (wid >= n) return;
    int beg = rowptr[wid], end = rowptr[wid + 1];
    int c = lane & 7, e8 = lane >> 3;
    float acc = 0.f;
    for (int j = beg + e8; j < end; j += 8) {
        int s = csr[j];
        acc += h2p[(size_t)s * NC + c];
    }
    acc += __shfl_xor(acc, 8, 64);
    acc += __shfl_xor(acc, 16, 64);
    acc += __shfl_xor(acc, 32, 64);
    float v = acc * in_norm[wid] + b2[c];
    float m = v;
    m = fmaxf(m, __shfl_xor(m, 1, 64));
    m = fmaxf(m, __shfl_xor(m, 2, 64));
    m = fmaxf(m, __shfl_xor(m, 4, 64));
    float ev = __expf(v - m);
    float s8 = ev;
    s8 += __shfl_xor(s8, 1, 64);
    s8 += __shfl_xor(s8, 2, 64);
    s8 += __shfl_xor(s8, 4, 64);
    if (e8 == 0) out[(size_t)wid * NC + c] = ev / s8;
}

extern "C" void kernel_launch(void* const* d_in, const int* in_sizes, int n_in,
                              void* d_out, int out_size, void* d_ws, size_t ws_size,
                              hipStream_t stream) {
    const float* x   = (const float*)d_in[0];
    const int*   src = (const int*)d_in[1];
    const int*   dst = (const int*)d_in[2];
    const float* W1  = (const float*)d_in[3];
    const float* b1  = (const float*)d_in[4];
    const float* W2  = (const float*)d_in[5];
    const float* b2  = (const float*)d_in[6];
    float* out = (float*)d_out;

    const int N = in_sizes[0] / IN_DIM;   // 100000
    const int E = in_sizes[1];            // 3200000
    const int NB = (N + 255) / 256;       // 391 (<= 512)

    float* ws = (float*)d_ws;
    float* out_norm = ws;                           // N  (degrees during build)
    float* in_norm  = ws + (size_t)N;               // N
    float* h0       = ws + (size_t)2 * N;           // 64N
    float* h2p      = ws + (size_t)66 * N;          // 8N
    int*   rowptr   = (int*)(ws + (size_t)74 * N);  // N+1
    int*   cursor   = rowptr + (N + 1);             // N
    int*   bsum     = cursor + N;                   // 512
    int*   csr      = bsum + 512;                   // E
    // total: 74N floats + (2N+513+E) ints ~ 43 MB

    hipMemsetAsync(out_norm, 0, (size_t)2 * N * sizeof(float), stream);

    hist_k<<<(E + 255) / 256, 256, 0, stream>>>(src, dst, out_norm, in_norm, E);
    scanA<<<NB, 256, 0, stream>>>(in_norm, bsum, N);
    scanB<<<1, 512, 0, stream>>>(bsum, NB, rowptr, N);
    scanC<<<NB, 256, 0, stream>>>(in_norm, bsum, rowptr, cursor, N);
    norm_k<<<(N + 255) / 256, 256, 0, stream>>>(out_norm, in_norm, N);
    fill_k<<<(E + 255) / 256, 256, 0, stream>>>(src, dst, cursor, csr, E);
    gemm1_k<<<(N + 63) / 64, 256, 0, stream>>>(x, W1, out_norm, h0, N);
    agg1proj_k<<<(N + 3) / 4, 256, 0, stream>>>(rowptr, csr, h0, in_norm, out_norm, b1, W2, h2p, N);
    agg2smax_k<<<(N + 3) / 4, 256, 0, stream>>>(rowptr, csr, h2p, in_norm, b2, out, N);
}

// Round 4
// 824.412 us; speedup vs baseline: 1.6786x; 1.0887x over previous
//
#include <hip/hip_runtime.h>
#include <hip/hip_bf16.h>

// GCN 2-layer forward, CSR pull aggregation + XCD-replicated histograms.
// x[N,128] f32, src[E], dst[E] i32, W1[128,64], b1[64], W2[64,8], b2[8]
// out: softmax probs [N,8] f32.

#define IN_DIM 128
#define HID 64
#define NC 8
#define REP 8        // one histogram replica per XCD (blockIdx & 7 ~ XCD under round-robin)
#define XS_LD 132    // padded leading dim for x tile in LDS

// replicated degree histograms: replica r = blockIdx & 7 keeps atomics inside one XCD's L2
__global__ void hist_k(const int* __restrict__ src, const int* __restrict__ dst,
                       int* __restrict__ cout_, int* __restrict__ cin_, int e, int n) {
    int i = blockIdx.x * blockDim.x + threadIdx.x;
    int r = blockIdx.x & (REP - 1);
    if (i < e) {
        atomicAdd(&cout_[r * n + src[i]], 1);
        atomicAdd(&cin_[r * n + dst[i]], 1);
    }
}

// sum replicas -> degrees & norms; rewrite cin_ to per-replica exclusive prefix (for fill bases)
__global__ void reduce_k(int* __restrict__ cin_, const int* __restrict__ cout_,
                         float* __restrict__ out_norm, float* __restrict__ in_norm,
                         int* __restrict__ indeg, int n) {
    int v = blockIdx.x * blockDim.x + threadIdx.x;
    if (v >= n) return;
    int run = 0;
#pragma unroll
    for (int r = 0; r < REP; ++r) {
        int c = cin_[r * n + v];
        cin_[r * n + v] = run;
        run += c;
    }
    indeg[v] = run;
    int outd = 0;
#pragma unroll
    for (int r = 0; r < REP; ++r) outd += cout_[r * n + v];
    in_norm[v]  = rsqrtf(fmaxf((float)run, 1.0f));
    out_norm[v] = rsqrtf(fmaxf((float)outd, 1.0f));
}

// block sums of in-degree
__global__ void scanA(const int* __restrict__ indeg, int* __restrict__ bsum, int n) {
    int t = threadIdx.x;
    int i = blockIdx.x * 256 + t;
    int v = (i < n) ? indeg[i] : 0;
#pragma unroll
    for (int d = 1; d < 64; d <<= 1) v += __shfl_xor(v, d, 64);
    __shared__ int w4[4];
    if ((t & 63) == 0) w4[t >> 6] = v;
    __syncthreads();
    if (t == 0) bsum[blockIdx.x] = w4[0] + w4[1] + w4[2] + w4[3];
}

// exclusive scan of block sums (nb <= 512), also writes rowptr[n] = E
__global__ void scanB(int* __restrict__ bsum, int nb, int* __restrict__ rowptr, int n) {
    __shared__ int s[512];
    int t = threadIdx.x;
    s[t] = (t < nb) ? bsum[t] : 0;
    __syncthreads();
    for (int d = 1; d < 512; d <<= 1) {
        int v = (t >= d) ? s[t - d] : 0;
        __syncthreads();
        s[t] += v;
        __syncthreads();
    }
    if (t < nb) bsum[t] = t ? s[t - 1] : 0;
    if (t == 0) rowptr[n] = s[nb - 1];
}

// per-block exclusive scan + block offset -> rowptr; init per-replica cursors
__global__ void scanC(const int* __restrict__ indeg, const int* __restrict__ bsum,
                      const int* __restrict__ cin_, int* __restrict__ rowptr,
                      int* __restrict__ cursor, int n) {
    __shared__ int s[256];
    int t = threadIdx.x;
    int i = blockIdx.x * 256 + t;
    int v = (i < n) ? indeg[i] : 0;
    s[t] = v;
    __syncthreads();
    for (int d = 1; d < 256; d <<= 1) {
        int u = (t >= d) ? s[t - d] : 0;
        __syncthreads();
        s[t] += u;
        __syncthreads();
    }
    if (i < n) {
        int ex = bsum[blockIdx.x] + s[t] - v;
        rowptr[i] = ex;
#pragma unroll
        for (int r = 0; r < REP; ++r) cursor[r * n + i] = ex + cin_[r * n + i];
    }
}

// scatter edge sources into CSR slots; replica cursors keep atomics XCD-local
__global__ void fill_k(const int* __restrict__ src, const int* __restrict__ dst,
                       int* __restrict__ cursor, int* __restrict__ csr, int e, int n) {
    int i = blockIdx.x * blockDim.x + threadIdx.x;
    int r = blockIdx.x & (REP - 1);
    if (i < e) {
        int d = dst[i];
        int slot = atomicAdd(&cursor[r * n + d], 1);
        csr[slot] = src[i];
    }
}

// h0[i][j] = out_norm[i] * (x[i] @ W1)[j]; 64x64 tile, 4x4 per thread
__global__ __launch_bounds__(256) void gemm1_k(const float* __restrict__ x, const float* __restrict__ W1,
                        const float* __restrict__ out_norm, float* __restrict__ h0, int n) {
    __shared__ float xs[64 * XS_LD];
    __shared__ float Ws[IN_DIM * HID];
    int t = threadIdx.x;
    int row0 = blockIdx.x * 64;
#pragma unroll
    for (int j = 0; j < 8; ++j) {
        int f4 = t + j * 256;
        *(float4*)&Ws[f4 * 4] = ((const float4*)W1)[f4];
    }
#pragma unroll
    for (int j = 0; j < 8; ++j) {
        int f4 = t + j * 256;
        int r = f4 >> 5;
        int k = (f4 & 31) * 4;
        float4 v = (row0 + r < n) ? ((const float4*)x)[(size_t)(row0 + r) * 32 + (f4 & 31)]
                                  : make_float4(0.f, 0.f, 0.f, 0.f);
        *(float4*)&xs[r * XS_LD + k] = v;
    }
    __syncthreads();
    int rq = (t >> 4) * 4;
    int cq = (t & 15) * 4;
    float acc[4][4] = {};
    for (int k = 0; k < IN_DIM; k += 4) {
        float4 xr[4], wc[4];
#pragma unroll
        for (int i = 0; i < 4; ++i) xr[i] = *(const float4*)&xs[(rq + i) * XS_LD + k];
#pragma unroll
        for (int kk = 0; kk < 4; ++kk) wc[kk] = *(const float4*)&Ws[(k + kk) * HID + cq];
#pragma unroll
        for (int i = 0; i < 4; ++i) {
            float xv0 = xr[i].x, xv1 = xr[i].y, xv2 = xr[i].z, xv3 = xr[i].w;
            acc[i][0] += xv0 * wc[0].x + xv1 * wc[1].x + xv2 * wc[2].x + xv3 * wc[3].x;
            acc[i][1] += xv0 * wc[0].y + xv1 * wc[1].y + xv2 * wc[2].y + xv3 * wc[3].y;
            acc[i][2] += xv0 * wc[0].z + xv1 * wc[1].z + xv2 * wc[2].z + xv3 * wc[3].z;
            acc[i][3] += xv0 * wc[0].w + xv1 * wc[1].w + xv2 * wc[2].w + xv3 * wc[3].w;
        }
    }
#pragma unroll
    for (int i = 0; i < 4; ++i) {
        int row = row0 + rq + i;
        if (row < n) {
            float onn = out_norm[row];
            float4 o = make_float4(acc[i][0] * onn, acc[i][1] * onn, acc[i][2] * onn, acc[i][3] * onn);
            *(float4*)&h0[(size_t)row * HID + cq] = o;
        }
    }
}

// wave per dst node: pull-aggregate h0 rows, relu/norm/bias + W2 projection
__global__ void agg1proj_k(const int* __restrict__ rowptr, const int* __restrict__ csr,
                           const float* __restrict__ h0, const float* __restrict__ in_norm,
                           const float* __restrict__ out_norm, const float* __restrict__ b1,
                           const float* __restrict__ W2, float* __restrict__ h2p, int n) {
    int wid = (blockIdx.x * blockDim.x + threadIdx.x) >> 6;
    int lane = threadIdx.x & 63;
    if (wid >= n) return;
    int beg = rowptr[wid], end = rowptr[wid + 1];
    float acc = 0.f;
    int j = beg;
    for (; j + 4 <= end; j += 4) {
        int s0 = csr[j], s1 = csr[j + 1], s2 = csr[j + 2], s3 = csr[j + 3];
        acc += h0[(size_t)s0 * HID + lane];
        acc += h0[(size_t)s1 * HID + lane];
        acc += h0[(size_t)s2 * HID + lane];
        acc += h0[(size_t)s3 * HID + lane];
    }
    for (; j < end; ++j) acc += h0[(size_t)csr[j] * HID + lane];
    float v = fmaxf(acc * in_norm[wid] + b1[lane], 0.f);
    float onn = out_norm[wid];
    float res = 0.f;
#pragma unroll
    for (int c = 0; c < NC; ++c) {
        float p = v * W2[lane * NC + c];
        p += __shfl_xor(p, 1, 64);
        p += __shfl_xor(p, 2, 64);
        p += __shfl_xor(p, 4, 64);
        p += __shfl_xor(p, 8, 64);
        p += __shfl_xor(p, 16, 64);
        p += __shfl_xor(p, 32, 64);
        if (lane == c) res = p;
    }
    if (lane < NC) h2p[(size_t)wid * NC + lane] = onn * res;
}

// wave per dst node: pull-aggregate h2p rows, bias + softmax
__global__ void agg2smax_k(const int* __restrict__ rowptr, const int* __restrict__ csr,
                           const float* __restrict__ h2p, const float* __restrict__ in_norm,
                           const float* __restrict__ b2, float* __restrict__ out, int n) {
    int wid = (blockIdx.x * blockDim.x + threadIdx.x) >> 6;
    int lane = threadIdx.x & 63;
    if (wid >= n) return;
    int beg = rowptr[wid], end = rowptr[wid + 1];
    int c = lane & 7, e8 = lane >> 3;
    float acc = 0.f;
    for (int j = beg + e8; j < end; j += 8) {
        acc += h2p[(size_t)csr[j] * NC + c];
    }
    acc += __shfl_xor(acc, 8, 64);
    acc += __shfl_xor(acc, 16, 64);
    acc += __shfl_xor(acc, 32, 64);
    float v = acc * in_norm[wid] + b2[c];
    float m = v;
    m = fmaxf(m, __shfl_xor(m, 1, 64));
    m = fmaxf(m, __shfl_xor(m, 2, 64));
    m = fmaxf(m, __shfl_xor(m, 4, 64));
    float ev = __expf(v - m);
    float s8 = ev;
    s8 += __shfl_xor(s8, 1, 64);
    s8 += __shfl_xor(s8, 2, 64);
    s8 += __shfl_xor(s8, 4, 64);
    if (e8 == 0) out[(size_t)wid * NC + c] = ev / s8;
}

extern "C" void kernel_launch(void* const* d_in, const int* in_sizes, int n_in,
                              void* d_out, int out_size, void* d_ws, size_t ws_size,
                              hipStream_t stream) {
    const float* x   = (const float*)d_in[0];
    const int*   src = (const int*)d_in[1];
    const int*   dst = (const int*)d_in[2];
    const float* W1  = (const float*)d_in[3];
    const float* b1  = (const float*)d_in[4];
    const float* W2  = (const float*)d_in[5];
    const float* b2  = (const float*)d_in[6];
    float* out = (float*)d_out;

    const int N = in_sizes[0] / IN_DIM;   // 100000
    const int E = in_sizes[1];            // 3200000
    const int NB = (N + 255) / 256;       // 391 (<= 512)

    float* ws = (float*)d_ws;
    float* out_norm = ws;                           // N
    float* in_norm  = ws + (size_t)N;               // N
    float* h0       = ws + (size_t)2 * N;           // 64N
    float* h2p      = ws + (size_t)66 * N;          // 8N
    int*   ibase    = (int*)(ws + (size_t)74 * N);
    int*   cin      = ibase;                        // 8N
    int*   cout_    = cin + (size_t)REP * N;        // 8N
    int*   cursor   = cout_ + (size_t)REP * N;      // 8N
    int*   indeg    = cursor + (size_t)REP * N;     // N
    int*   rowptr   = indeg + N;                    // N+1
    int*   bsum     = rowptr + (N + 1);             // 512
    int*   csr      = bsum + 512;                   // E
    // total ~ 29.6 MB floats + ~22.9 MB ints

    hipMemsetAsync(cin, 0, (size_t)2 * REP * N * sizeof(int), stream);

    hist_k<<<(E + 255) / 256, 256, 0, stream>>>(src, dst, cout_, cin, E, N);
    reduce_k<<<(N + 255) / 256, 256, 0, stream>>>(cin, cout_, out_norm, in_norm, indeg, N);
    scanA<<<NB, 256, 0, stream>>>(indeg, bsum, N);
    scanB<<<1, 512, 0, stream>>>(bsum, NB, rowptr, N);
    scanC<<<NB, 256, 0, stream>>>(indeg, bsum, cin, rowptr, cursor, N);
    fill_k<<<(E + 255) / 256, 256, 0, stream>>>(src, dst, cursor, csr, E, N);
    gemm1_k<<<(N + 63) / 64, 256, 0, stream>>>(x, W1, out_norm, h0, N);
    agg1proj_k<<<(N + 3) / 4, 256, 0, stream>>>(rowptr, csr, h0, in_norm, out_norm, b1, W2, h2p, N);
    agg2smax_k<<<(N + 3) / 4, 256, 0, stream>>>(rowptr, csr, h2p, in_norm, b2, out, N);
}